// Round 9
// baseline (72279.932 us; speedup 1.0000x reference)
//
#include <hip/hip_runtime.h>
#include <hip/hip_cooperative_groups.h>
#include <cstddef>
#include <cstdint>

namespace cg = cooperative_groups;

#define T_INN 200
#define T_OUTT 400
#define BB 64
#define DENC 512
#define NMEL 80

typedef unsigned short u16;
typedef __bf16 bf16x8 __attribute__((ext_vector_type(8)));
typedef float f32x4 __attribute__((ext_vector_type(4)));

// fast sigmoid/tanh (validated R5-R8: absmax unchanged at 0.00098)
__device__ __forceinline__ float sigf(float x) {
  return __builtin_amdgcn_rcpf(1.0f + __expf(-x));
}
__device__ __forceinline__ float ftanh(float x) {
  float e2 = __expf(2.0f * x);
  return 1.0f - 2.0f * __builtin_amdgcn_rcpf(e2 + 1.0f);
}

// round-to-nearest-even f32 -> bf16
__device__ __forceinline__ u16 f2bf(float f) {
  unsigned u = __float_as_uint(f);
  unsigned r = u + 0x7fffu + ((u >> 16) & 1u);
  return (u16)(r >> 16);
}

__device__ __forceinline__ bf16x8 ldbf8(const u16* p) { return *(const bf16x8*)p; }

// ---------------------------------------------------------------------------
// fp32 tiled GEMM for precompute: C[m][n] = act(sum_k A[m][k]*W[n][k])
// ---------------------------------------------------------------------------
__global__ __launch_bounds__(256) void gemm_pre_kernel(
    const float* __restrict__ A, int lda, const float* __restrict__ W, int ldw,
    float* __restrict__ C, u16* __restrict__ Cbf, int ldc, int K, int relu)
{
  __shared__ float As[16][66];
  __shared__ float Ws[16][66];
  const int tid = threadIdx.x;
  const int tn = tid & 15, tm = tid >> 4;
  const int n0 = blockIdx.x * 64;
  const int m0 = blockIdx.y * 64;
  float acc[4][4] = {{0.f}};
  for (int kt = 0; kt < K; kt += 16) {
#pragma unroll
    for (int i = 0; i < 4; i++) {
      int e = tid + 256 * i;
      int m = e >> 4, kk = e & 15;
      As[kk][m] = A[(size_t)(m0 + m) * lda + kt + kk];
    }
#pragma unroll
    for (int i = 0; i < 4; i++) {
      int e = tid + 256 * i;
      int n = e >> 4, kk = e & 15;
      Ws[kk][n] = W[(size_t)(n0 + n) * ldw + kt + kk];
    }
    __syncthreads();
#pragma unroll
    for (int kk = 0; kk < 16; kk++) {
      float2 a01 = *(const float2*)&As[kk][tm * 4];
      float2 a23 = *(const float2*)&As[kk][tm * 4 + 2];
      float2 w01 = *(const float2*)&Ws[kk][tn * 4];
      float2 w23 = *(const float2*)&Ws[kk][tn * 4 + 2];
      float a[4] = {a01.x, a01.y, a23.x, a23.y};
      float w[4] = {w01.x, w01.y, w23.x, w23.y};
#pragma unroll
      for (int mi = 0; mi < 4; mi++)
#pragma unroll
        for (int ni = 0; ni < 4; ni++)
          acc[mi][ni] = fmaf(a[mi], w[ni], acc[mi][ni]);
    }
    __syncthreads();
  }
#pragma unroll
  for (int mi = 0; mi < 4; mi++) {
    int m = m0 + tm * 4 + mi;
    float v0 = acc[mi][0], v1 = acc[mi][1], v2 = acc[mi][2], v3 = acc[mi][3];
    if (relu) {
      v0 = fmaxf(v0, 0.f); v1 = fmaxf(v1, 0.f);
      v2 = fmaxf(v2, 0.f); v3 = fmaxf(v3, 0.f);
    }
    if (Cbf) {
      u16* p = Cbf + (size_t)m * ldc + n0 + tn * 4;
      p[0] = f2bf(v0); p[1] = f2bf(v1); p[2] = f2bf(v2); p[3] = f2bf(v3);
    } else {
      float4 vv; vv.x = v0; vv.y = v1; vv.z = v2; vv.w = v3;
      *(float4*)&C[(size_t)m * ldc + n0 + tn * 4] = vv;
    }
  }
}

// ---------------------------------------------------------------------------
// Weight repack: W[n][k] fp32 -> bf16, MFMA B-fragment lane order.
// ---------------------------------------------------------------------------
__global__ __launch_bounds__(256) void pack_w_kernel(
    const float* __restrict__ W, u16* __restrict__ P,
    int K, int KTl, int ktOff, int KTtot, int total)
{
  int slot = blockIdx.x * 256 + threadIdx.x;
  if (slot >= total) return;
  int lane = slot & 63;
  int ktl = (slot >> 6) % KTl;
  int nt = slot / (64 * KTl);
  int n = nt * 16 + (lane & 15);
  int k = ktl * 32 + (lane >> 4) * 8;
  const float* src = W + (size_t)n * K + k;
  u16 tmp[8];
#pragma unroll
  for (int i = 0; i < 8; i++) tmp[i] = f2bf(src[i]);
  u16* dst = P + ((size_t)(nt * KTtot + (ktl + ktOff)) * 64 + lane) * 8;
  *(uint4*)dst = *(const uint4*)tmp;
}

// pm (b*t, a) -> pmT (b, a, t)
__global__ void transpose_pm_kernel(const float* __restrict__ pm, float* __restrict__ pmT)
{
  int b = blockIdx.z;
  int tT = blockIdx.x * 32, aT = blockIdx.y * 32;
  __shared__ float tile[32][33];
  int tx = threadIdx.x, ty = threadIdx.y;
#pragma unroll
  for (int i = 0; i < 4; i++) {
    int t = tT + ty + i * 8;
    int a = aT + tx;
    if (t < T_INN) tile[ty + i * 8][tx] = pm[((size_t)b * T_INN + t) * 128 + a];
  }
  __syncthreads();
#pragma unroll
  for (int i = 0; i < 4; i++) {
    int a = aT + ty + i * 8;
    int t = tT + tx;
    if (t < T_INN) pmT[((size_t)b * 128 + a) * T_INN + t] = tile[tx][ty + i * 8];
  }
}

// ---------------------------------------------------------------------------
// Persistent cooperative decode kernel, 256 blocks x 1024 threads (16 waves;
// LDS 72KB, VGPR <= 128 via launch_bounds -> exactly 1 block/CU).
// Per step t: phase A = gatesD(t-1) ; gatesA(t)   (all 256 blocks, R8 bodies)
//             grid.sync
//             phase B = attention(t) [blocks 0-63] || outproj(t-1) [64-127]
//             grid.sync
// Hazard audit: all cross-block RAW/WAR pairs separated by grid.sync or by
// parity slots (ah_bf/dh_bf/actx two-slot; actx_bf written only in phase B,
// read only in phase A; aw/awcum/ac/dc block- or tile-private).
// ---------------------------------------------------------------------------
struct SmemGates {
  float part[16][16][66];   // [kw][gate*4+reg][lane(+pad)] conflict-free
  float gred[1024];
};
struct SmemAtt {
  float2 acS[T_INN];        // (aw, awcum) merged -> ds_read_b64
  float ahS[1024];
  float pp[128][9];
  float pqS[128];
  float convS[T_INN][33];
  float ep[4][256];
  float red[256];
  float awS[256];
  float cpart[1024];
};
union Smem { SmemGates g; SmemAtt a; };

struct DecParams {
  const u16* xs_bf;        // [400][64][256]
  u16* Wa;                 // packed, KT=64 (zero-padded from 56)
  u16* Wd;                 // packed, KT=80
  const float* b_a; const float* b_d;
  float* ah; float* ac; float* dh; float* dc;
  u16* ah_bf;              // [2][64][1024] parity
  u16* dh_bf;              // [2][64][1024] parity
  float* actx;             // [2][64][512] parity
  u16* actx_bf;            // [64][512]
  float* aw; float* awcum;
  const float* pmT;
  const float* Wq; const float* Wconv; const float* Wloc; const float* vvec;
  const int* lens; const float* enc;
  const float* Wp; const float* bp;
  float* outsOut; float* alignsOut;
};

// R8 gates body, verbatim math. Z=0: gatesA(t) KT=64; Z=1: gatesD(t-1) KT=80.
template <int Z>
__device__ __forceinline__ void gates_body(
    const DecParams& p, int bq, int ms, int tid, SmemGates& sg, int t)
{
  const int kw = tid >> 6, lane = tid & 63;
  const int mrow = lane & 15, ksub = (lane >> 4) * 8;
  const int row = ms * 16 + mrow;

  f32x4 acc0 = {0.f, 0.f, 0.f, 0.f};
  f32x4 acc1 = acc0, acc2 = acc0, acc3 = acc0;
  const float* bias; float* hF; float* cSt; u16* hw;

  if constexpr (Z == 0) {
    // gatesA(t): A = [xs(256) | actx(512) | ah(1024) | pad(256, W=0)]
    const u16* xs = p.xs_bf + (size_t)t * 64 * 256;
    const u16* ah_bf_r = p.ah_bf + (size_t)((t + 1) & 1) * 65536;
    constexpr int KT = 64;
    const size_t gstride = (size_t)KT * 32768;
    const u16* wb0 = p.Wa + ((size_t)(bq * KT + kw * 4) * 64 + lane) * 8;
    const u16* rb;
    if (kw < 2)      rb = xs        + (size_t)row * 256  + ksub + kw * 128;
    else if (kw < 6) rb = p.actx_bf + (size_t)row * 512  + ksub + kw * 128 - 256;
    else             rb = ah_bf_r   + (size_t)row * 1024 + ksub + kw * 128 - 768;
#pragma unroll
    for (int i = 0; i < 4; i++) {
      bf16x8 a = ldbf8(rb + i * 32);
      const u16* wb = wb0 + (size_t)i * 512;
      bf16x8 w0 = ldbf8(wb);
      bf16x8 w1 = ldbf8(wb + gstride);
      bf16x8 w2 = ldbf8(wb + 2 * gstride);
      bf16x8 w3 = ldbf8(wb + 3 * gstride);
      acc0 = __builtin_amdgcn_mfma_f32_16x16x32_bf16(a, w0, acc0, 0, 0, 0);
      acc1 = __builtin_amdgcn_mfma_f32_16x16x32_bf16(a, w1, acc1, 0, 0, 0);
      acc2 = __builtin_amdgcn_mfma_f32_16x16x32_bf16(a, w2, acc2, 0, 0, 0);
      acc3 = __builtin_amdgcn_mfma_f32_16x16x32_bf16(a, w3, acc3, 0, 0, 0);
    }
    bias = p.b_a; hF = p.ah; cSt = p.ac;
    hw = p.ah_bf + (size_t)(t & 1) * 65536;
  } else {
    // gatesD(t-1): A = [ah(t-1)(1024) | actx(t-1)(512) | dh(t-2)(1024)], KT=80
    const u16* ah_bf_r = p.ah_bf + (size_t)((t + 1) & 1) * 65536;
    const u16* dh_bf_r = p.dh_bf + (size_t)(t & 1) * 65536;
    constexpr int KT = 80;
    const size_t gstride = (size_t)KT * 32768;
    const u16* wb0 = p.Wd + ((size_t)(bq * KT + kw) * 64 + lane) * 8;
    const u16* a0b = ah_bf_r   + (size_t)row * 1024 + ksub + kw * 32;
    const u16* a1b = p.actx_bf + (size_t)row * 512  + ksub + kw * 32;
    const u16* a2b = dh_bf_r   + (size_t)row * 1024 + ksub + kw * 32;
#pragma unroll
    for (int i = 0; i < 5; i++) {
      const u16* ap = (i < 2) ? (a0b + i * 512) : ((i == 2) ? a1b : (a2b + (i - 3) * 512));
      bf16x8 a = ldbf8(ap);
      const u16* wb = wb0 + (size_t)i * (16 * 512);
      bf16x8 w0 = ldbf8(wb);
      bf16x8 w1 = ldbf8(wb + gstride);
      bf16x8 w2 = ldbf8(wb + 2 * gstride);
      bf16x8 w3 = ldbf8(wb + 3 * gstride);
      acc0 = __builtin_amdgcn_mfma_f32_16x16x32_bf16(a, w0, acc0, 0, 0, 0);
      acc1 = __builtin_amdgcn_mfma_f32_16x16x32_bf16(a, w1, acc1, 0, 0, 0);
      acc2 = __builtin_amdgcn_mfma_f32_16x16x32_bf16(a, w2, acc2, 0, 0, 0);
      acc3 = __builtin_amdgcn_mfma_f32_16x16x32_bf16(a, w3, acc3, 0, 0, 0);
    }
    bias = p.b_d; hF = p.dh; cSt = p.dc;
    hw = p.dh_bf + (size_t)((t + 1) & 1) * 65536;
  }

  // conflict-free partial store: part[kw][gate*4+r][lane]
#pragma unroll
  for (int r = 0; r < 4; r++) {
    sg.part[kw][r][lane]      = acc0[r];
    sg.part[kw][4 + r][lane]  = acc1[r];
    sg.part[kw][8 + r][lane]  = acc2[r];
    sg.part[kw][12 + r][lane] = acc3[r];
  }
  __syncthreads();
  {
    int g = tid >> 8, rc = tid & 255, rw = rc >> 4, col = rc & 15;
    int ln = ((rw >> 2) << 4) + col;
    int r = g * 4 + (rw & 3);
    float s = 0.f;
#pragma unroll
    for (int k2 = 0; k2 < 16; k2++) s += sg.part[k2][r][ln];
    sg.gred[tid] = s;
  }
  __syncthreads();
  if (tid < 256) {
    int rw = tid >> 4, col = tid & 15;
    int j = bq * 16 + col, m = ms * 16 + rw;
    size_t idx = (size_t)m * 1024 + j;
    float gi = sg.gred[tid]       + bias[j];
    float gf = sg.gred[256 + tid] + bias[j + 1024];
    float gg = sg.gred[512 + tid] + bias[j + 2048];
    float go = sg.gred[768 + tid] + bias[j + 3072];
    float cn = sigf(gf) * cSt[idx] + sigf(gi) * ftanh(gg);
    cSt[idx] = cn;
    float hn = sigf(go) * ftanh(cn);
    hF[idx] = hn;
    hw[idx] = f2bf(hn);
  }
}

__global__ __launch_bounds__(1024, 4) void decode_kernel(DecParams p)
{
  cg::grid_group grid = cg::this_grid();
  const int b = blockIdx.x;
  const int bq = b & 63, ms = b >> 6;
  const int tid = threadIdx.x;
  const int g = tid >> 8, ti = tid & 255;

  __shared__ Smem sm;

  for (int t = 0; t <= T_OUTT; t++) {
    // ---------------- phase A: gatesD(t-1) then gatesA(t) -------------------
    if (t >= 1) {
      gates_body<1>(p, bq, ms, tid, sm.g, t);
      __syncthreads();
    }
    if (t < T_OUTT) {
      gates_body<0>(p, bq, ms, tid, sm.g, t);
    }
    grid.sync();

    // ---------------- phase B: attention(t) || outproj(t-1) -----------------
    if (b < 64) {
      if (t < T_OUTT) {
        SmemAtt& sa = sm.a;
        float* actxW = p.actx + (size_t)(t & 1) * 32768;
        if (tid < T_INN) {
          float2 v; v.x = p.aw[b * T_INN + tid]; v.y = p.awcum[b * T_INN + tid];
          sa.acS[tid] = v;
        }
        sa.ahS[tid] = p.ah[(size_t)b * 1024 + tid];
        __syncthreads();
        {
          int a = tid >> 3, kc = tid & 7;
          const float4* wv = (const float4*)(p.Wq + (size_t)a * 1024 + kc * 128);
          const float4* hv = (const float4*)(sa.ahS + kc * 128);
          float s = 0.f;
#pragma unroll 8
          for (int i = 0; i < 32; i++) {
            float4 wq = wv[i], hh = hv[i];
            s += wq.x * hh.x + wq.y * hh.y + wq.z * hh.z + wq.w * hh.w;
          }
          sa.pp[a][kc] = s;
        }
        __syncthreads();
        if (tid < 128) {
          float s = 0.f;
#pragma unroll
          for (int kc = 0; kc < 8; kc++) s += sa.pp[tid][kc];
          sa.pqS[tid] = s;
        }
        if (ti < T_INN) {
          // conv, k-outer: window element read ONCE (float2), 8 reg accs
          float sacc[8] = {0.f, 0.f, 0.f, 0.f, 0.f, 0.f, 0.f, 0.f};
#pragma unroll
          for (int k = 0; k < 31; k++) {
            int tt = ti + k - 15;
            if (tt >= 0 && tt < T_INN) {
              float2 v = sa.acS[tt];
#pragma unroll
              for (int f8 = 0; f8 < 8; f8++) {
                int f = g * 8 + f8;
                sacc[f8] += p.Wconv[f * 62 + k] * v.x + p.Wconv[f * 62 + 31 + k] * v.y;
              }
            }
          }
#pragma unroll
          for (int f8 = 0; f8 < 8; f8++) sa.convS[ti][g * 8 + f8] = sacc[f8];
        }
        __syncthreads();
        float e = 0.f;
        if (ti < T_INN) {
          float cv[32];
#pragma unroll
          for (int f = 0; f < 32; f++) cv[f] = sa.convS[ti][f];
          const float* pm = p.pmT + ((size_t)b * 128 + g * 32) * T_INN + ti;
#pragma unroll 4
          for (int aa = 0; aa < 32; aa++) {
            int a = g * 32 + aa;
            float x = sa.pqS[a] + pm[(size_t)aa * T_INN];
            const float* wl = p.Wloc + a * 32;
#pragma unroll
            for (int f = 0; f < 32; f++) x += wl[f] * cv[f];
            float ex2 = __expf(2.f * x);
            e += p.vvec[a] * (1.f - 2.f * __builtin_amdgcn_rcpf(ex2 + 1.f));
          }
        }
        sa.ep[g][ti] = e;
        __syncthreads();
        float ev = -3.0e38f, ex = 0.f;
        if (tid < 256) {
          if (tid < T_INN) {
            ev = sa.ep[0][tid] + sa.ep[1][tid] + sa.ep[2][tid] + sa.ep[3][tid];
            if (tid >= p.lens[b]) ev = -100000000.0f;
          }
          sa.red[tid] = ev;
        }
        __syncthreads();
        for (int s2 = 128; s2 > 0; s2 >>= 1) {
          if (tid < s2) sa.red[tid] = fmaxf(sa.red[tid], sa.red[tid + s2]);
          __syncthreads();
        }
        float mx = sa.red[0];
        __syncthreads();
        if (tid < 256) { ex = (tid < T_INN) ? __expf(ev - mx) : 0.f; sa.red[tid] = ex; }
        __syncthreads();
        for (int s2 = 128; s2 > 0; s2 >>= 1) {
          if (tid < s2) sa.red[tid] += sa.red[tid + s2];
          __syncthreads();
        }
        float inv = 1.0f / sa.red[0];
        if (tid < T_INN) {
          float a = ex * inv;
          sa.awS[tid] = a;
          p.aw[b * T_INN + tid] = a;
          p.awcum[b * T_INN + tid] = sa.acS[tid].y + a;
          p.alignsOut[((size_t)b * T_OUTT + t) * T_INN + tid] = a;
        }
        __syncthreads();
        {
          int e0 = tid & 511, half = tid >> 9;
          const float* ep2 = p.enc + ((size_t)b * T_INN + half * 100) * DENC + e0;
          float s = 0.f;
#pragma unroll 4
          for (int tt = 0; tt < 100; tt++)
            s += sa.awS[half * 100 + tt] * ep2[(size_t)tt * DENC];
          sa.cpart[tid] = s;
        }
        __syncthreads();
        if (tid < 512) {
          float v2 = sa.cpart[tid] + sa.cpart[512 + tid];
          actxW[b * DENC + tid] = v2;
          p.actx_bf[b * DENC + tid] = f2bf(v2);
        }
      }
    } else if (b < 128) {
      if (t >= 1) {
        const int bo = b - 64;
        const float* actxR = p.actx + (size_t)((t - 1) & 1) * 32768;
        float* cp = sm.g.gred;
        float s = 0.f;
        int m = tid / 12, sub = tid - m * 12;
        if (tid < 960) {
          const float4* w4 = (const float4*)(p.Wp + (size_t)m * 1536 + sub * 128);
          const float4* a4 = (sub < 8)
              ? (const float4*)(p.dh + (size_t)bo * 1024 + sub * 128)
              : (const float4*)(actxR + (size_t)bo * 512 + (sub - 8) * 128);
#pragma unroll 8
          for (int kk = 0; kk < 32; kk++) {
            float4 w = w4[kk], av = a4[kk];
            s += w.x * av.x + w.y * av.y + w.z * av.z + w.w * av.w;
          }
        }
        cp[tid] = s;
        __syncthreads();
        if (tid < 80) {
          float acc2 = p.bp[tid];
#pragma unroll
          for (int i2 = 0; i2 < 12; i2++) acc2 += cp[tid * 12 + i2];
          p.outsOut[((size_t)bo * T_OUTT + (t - 1)) * NMEL + tid] = acc2;
        }
      }
    }
    if (t == T_OUTT) break;
    grid.sync();
  }
}

extern "C" void kernel_launch(void* const* d_in, const int* in_sizes, int n_in,
                              void* d_out, int out_size, void* d_ws, size_t ws_size,
                              hipStream_t stream)
{
  const float* enc    = (const float*)d_in[0];
  const float* dec    = (const float*)d_in[1];
  const int*   lens   = (const int*)d_in[2];
  const float* W_p1   = (const float*)d_in[3];
  const float* W_p2   = (const float*)d_in[4];
  const float* W_ih_a = (const float*)d_in[5];
  const float* W_hh_a = (const float*)d_in[6];
  const float* b_a    = (const float*)d_in[7];
  const float* Wq     = (const float*)d_in[8];
  const float* Wmem   = (const float*)d_in[9];
  const float* vvec   = (const float*)d_in[10];
  const float* Wconv  = (const float*)d_in[11];
  const float* Wloc   = (const float*)d_in[12];
  const float* W_ih_d = (const float*)d_in[13];
  const float* W_hh_d = (const float*)d_in[14];
  const float* b_d    = (const float*)d_in[15];
  const float* Wp     = (const float*)d_in[16];
  const float* bp     = (const float*)d_in[17];

  float* ws = (float*)d_ws;
  size_t off = 0;
  u16* xs_bf = (u16*)(ws + off); off += (size_t)T_OUTT * 64 * 256 / 2;
  float* pmT = ws + off; off += (size_t)64 * 128 * T_INN;
  u16* Wa_pack = (u16*)(ws + off); off += (size_t)4096 * 2048 / 2;   // KT=64 padded
  u16* Wd_pack = (u16*)(ws + off); off += (size_t)4096 * 2560 / 2;   // KT=80
  // state block (zero-initialized)
  float* stateBase = ws + off;
  float* ah    = stateBase;            // f32 [64][1024]
  float* dh    = ah + 65536;
  float* ac    = dh + 65536;
  float* dc    = ac + 65536;
  float* actx  = dc + 65536;           // [2][64][512] parity
  float* aw    = actx + 2 * 32768;
  float* awcum = aw + 12800;
  u16* ah_bf   = (u16*)(awcum + 12800);     // [2][64][1024]
  u16* dh_bf   = ah_bf + 2 * 65536;         // [2][64][1024]
  u16* actx_bf = dh_bf + 2 * 65536;         // [64][512]
  size_t stateFloats = 4 * 65536 + 2 * 32768 + 2 * 12800
                     + (2 * 65536 + 2 * 65536 + 32768) / 2;
  off += stateFloats;
  float* scratch = ws + off;           // precompute only
  float* h1 = scratch;                 // 399*64 x 256
  float* pmt = scratch;                // reused after prenet

  float* outsOut   = (float*)d_out;
  float* alignsOut = outsOut + (size_t)BB * T_OUTT * NMEL;

  // zero recurrent state + t=0 prenet row; zero Wa_pack (KT padding)
  hipMemsetAsync(stateBase, 0, stateFloats * sizeof(float), stream);
  hipMemsetAsync(xs_bf, 0, (size_t)64 * 256 * sizeof(u16), stream);
  hipMemsetAsync(Wa_pack, 0, (size_t)4096 * 2048 * sizeof(u16), stream);

  // ---- precompute ----
  {
    int tot;
    tot = 256 * 24 * 64;
    pack_w_kernel<<<(tot + 255) / 256, 256, 0, stream>>>(W_ih_a, Wa_pack, 768, 24, 0, 64, tot);
    tot = 256 * 32 * 64;
    pack_w_kernel<<<(tot + 255) / 256, 256, 0, stream>>>(W_hh_a, Wa_pack, 1024, 32, 24, 64, tot);
    tot = 256 * 48 * 64;
    pack_w_kernel<<<(tot + 255) / 256, 256, 0, stream>>>(W_ih_d, Wd_pack, 1536, 48, 0, 80, tot);
    tot = 256 * 32 * 64;
    pack_w_kernel<<<(tot + 255) / 256, 256, 0, stream>>>(W_hh_d, Wd_pack, 1024, 32, 48, 80, tot);
  }
  gemm_pre_kernel<<<dim3(4, 399), 256, 0, stream>>>(dec, 80, W_p1, 80, h1, nullptr, 256, 80, 1);
  gemm_pre_kernel<<<dim3(4, 399), 256, 0, stream>>>(h1, 256, W_p2, 256, nullptr, xs_bf + 64 * 256, 256, 256, 1);
  gemm_pre_kernel<<<dim3(2, 200), 256, 0, stream>>>(enc, 512, Wmem, 512, pmt, nullptr, 128, 512, 0);
  transpose_pm_kernel<<<dim3(7, 4, 64), dim3(32, 8), 0, stream>>>(pmt, pmT);

  // ---- persistent cooperative decode loop (1 dispatch for all 400 steps) ----
  DecParams dp;
  dp.xs_bf = xs_bf; dp.Wa = Wa_pack; dp.Wd = Wd_pack;
  dp.b_a = b_a; dp.b_d = b_d;
  dp.ah = ah; dp.ac = ac; dp.dh = dh; dp.dc = dc;
  dp.ah_bf = ah_bf; dp.dh_bf = dh_bf;
  dp.actx = actx; dp.actx_bf = actx_bf;
  dp.aw = aw; dp.awcum = awcum;
  dp.pmT = pmT; dp.Wq = Wq; dp.Wconv = Wconv; dp.Wloc = Wloc; dp.vvec = vvec;
  dp.lens = lens; dp.enc = enc; dp.Wp = Wp; dp.bp = bp;
  dp.outsOut = outsOut; dp.alignsOut = alignsOut;

  void* kargs[] = { (void*)&dp };
  hipLaunchCooperativeKernel(decode_kernel, dim3(256), dim3(1024), kargs, 0, stream);
}

// Round 10
// 39419.952 us; speedup vs baseline: 1.8336x; 1.8336x over previous
//
#include <hip/hip_runtime.h>
#include <cstddef>
#include <cstdint>

#define T_INN 200
#define T_OUTT 400
#define BB 64
#define DENC 512
#define NMEL 80

typedef unsigned short u16;
typedef __bf16 bf16x8 __attribute__((ext_vector_type(8)));
typedef float f32x4 __attribute__((ext_vector_type(4)));

// fast sigmoid/tanh (validated R5-R8: absmax unchanged at 0.00098)
__device__ __forceinline__ float sigf(float x) {
  return __builtin_amdgcn_rcpf(1.0f + __expf(-x));
}
__device__ __forceinline__ float ftanh(float x) {
  float e2 = __expf(2.0f * x);
  return 1.0f - 2.0f * __builtin_amdgcn_rcpf(e2 + 1.0f);
}

// round-to-nearest-even f32 -> bf16
__device__ __forceinline__ u16 f2bf(float f) {
  unsigned u = __float_as_uint(f);
  unsigned r = u + 0x7fffu + ((u >> 16) & 1u);
  return (u16)(r >> 16);
}

__device__ __forceinline__ bf16x8 ldbf8(const u16* p) { return *(const bf16x8*)p; }

// ---------------------------------------------------------------------------
// fp32 tiled GEMM for precompute: C[m][n] = act(sum_k A[m][k]*W[n][k])
// ---------------------------------------------------------------------------
__global__ __launch_bounds__(256) void gemm_pre_kernel(
    const float* __restrict__ A, int lda, const float* __restrict__ W, int ldw,
    float* __restrict__ C, u16* __restrict__ Cbf, int ldc, int K, int relu)
{
  __shared__ float As[16][66];
  __shared__ float Ws[16][66];
  const int tid = threadIdx.x;
  const int tn = tid & 15, tm = tid >> 4;
  const int n0 = blockIdx.x * 64;
  const int m0 = blockIdx.y * 64;
  float acc[4][4] = {{0.f}};
  for (int kt = 0; kt < K; kt += 16) {
#pragma unroll
    for (int i = 0; i < 4; i++) {
      int e = tid + 256 * i;
      int m = e >> 4, kk = e & 15;
      As[kk][m] = A[(size_t)(m0 + m) * lda + kt + kk];
    }
#pragma unroll
    for (int i = 0; i < 4; i++) {
      int e = tid + 256 * i;
      int n = e >> 4, kk = e & 15;
      Ws[kk][n] = W[(size_t)(n0 + n) * ldw + kt + kk];
    }
    __syncthreads();
#pragma unroll
    for (int kk = 0; kk < 16; kk++) {
      float2 a01 = *(const float2*)&As[kk][tm * 4];
      float2 a23 = *(const float2*)&As[kk][tm * 4 + 2];
      float2 w01 = *(const float2*)&Ws[kk][tn * 4];
      float2 w23 = *(const float2*)&Ws[kk][tn * 4 + 2];
      float a[4] = {a01.x, a01.y, a23.x, a23.y};
      float w[4] = {w01.x, w01.y, w23.x, w23.y};
#pragma unroll
      for (int mi = 0; mi < 4; mi++)
#pragma unroll
        for (int ni = 0; ni < 4; ni++)
          acc[mi][ni] = fmaf(a[mi], w[ni], acc[mi][ni]);
    }
    __syncthreads();
  }
#pragma unroll
  for (int mi = 0; mi < 4; mi++) {
    int m = m0 + tm * 4 + mi;
    float v0 = acc[mi][0], v1 = acc[mi][1], v2 = acc[mi][2], v3 = acc[mi][3];
    if (relu) {
      v0 = fmaxf(v0, 0.f); v1 = fmaxf(v1, 0.f);
      v2 = fmaxf(v2, 0.f); v3 = fmaxf(v3, 0.f);
    }
    if (Cbf) {
      u16* p = Cbf + (size_t)m * ldc + n0 + tn * 4;
      p[0] = f2bf(v0); p[1] = f2bf(v1); p[2] = f2bf(v2); p[3] = f2bf(v3);
    } else {
      float4 vv; vv.x = v0; vv.y = v1; vv.z = v2; vv.w = v3;
      *(float4*)&C[(size_t)m * ldc + n0 + tn * 4] = vv;
    }
  }
}

// ---------------------------------------------------------------------------
// Weight repack: W[n][k] fp32 -> bf16, MFMA B-fragment lane order.
// ---------------------------------------------------------------------------
__global__ __launch_bounds__(256) void pack_w_kernel(
    const float* __restrict__ W, u16* __restrict__ P,
    int K, int KTl, int ktOff, int KTtot, int total)
{
  int slot = blockIdx.x * 256 + threadIdx.x;
  if (slot >= total) return;
  int lane = slot & 63;
  int ktl = (slot >> 6) % KTl;
  int nt = slot / (64 * KTl);
  int n = nt * 16 + (lane & 15);
  int k = ktl * 32 + (lane >> 4) * 8;
  const float* src = W + (size_t)n * K + k;
  u16 tmp[8];
#pragma unroll
  for (int i = 0; i < 8; i++) tmp[i] = f2bf(src[i]);
  u16* dst = P + ((size_t)(nt * KTtot + (ktl + ktOff)) * 64 + lane) * 8;
  *(uint4*)dst = *(const uint4*)tmp;
}

// pm (b*t, a) -> pmT (b, a, t)
__global__ void transpose_pm_kernel(const float* __restrict__ pm, float* __restrict__ pmT)
{
  int b = blockIdx.z;
  int tT = blockIdx.x * 32, aT = blockIdx.y * 32;
  __shared__ float tile[32][33];
  int tx = threadIdx.x, ty = threadIdx.y;
#pragma unroll
  for (int i = 0; i < 4; i++) {
    int t = tT + ty + i * 8;
    int a = aT + tx;
    if (t < T_INN) tile[ty + i * 8][tx] = pm[((size_t)b * T_INN + t) * 128 + a];
  }
  __syncthreads();
#pragma unroll
  for (int i = 0; i < 4; i++) {
    int a = aT + ty + i * 8;
    int t = tT + tx;
    if (t < T_INN) pmT[((size_t)b * 128 + a) * T_INN + t] = tile[tx][ty + i * 8];
  }
}

// ---------------------------------------------------------------------------
// Gates partial kernel: grid (64 quads, 2 k-chunks, 3), 1024 threads.
// Weight dedup: ALL 4 m-slices in one block (16 waves = 4 kw x 4 msw; the 4
// msw waves share identical W loads -> each weight element read ONCE per
// (quad,kc) -> total weight traffic 38 MB/step (was 152 in R8).
//   z=0: ga(t) partial for K-half kc      [t < 400]
//   z=1: gd(t-1) partial for K-half kc    [1 <= t <= 400]
//   z=2: outproj(t-2), m-half kc          [t >= 2]
// Partials -> gpa/gpd [2][64][4096] f32 (4 MB/step w + 4 MB r: 8% of R5's).
// Activation moved to fused kernel (batch-local there).
// ---------------------------------------------------------------------------
__global__ __launch_bounds__(1024) void gates_kernel(
    const u16* __restrict__ xs,        // [64][256] prenet rows for step t
    const u16* __restrict__ actx_bf,   // [64][512]   (state at t-1)
    const u16* __restrict__ ah_bf,     // [64][1024]  (ah(t-1))
    const u16* __restrict__ dh_bf,     // [64][1024]  (dh(t-2))
    const u16* __restrict__ Wa, const u16* __restrict__ Wd,
    float* __restrict__ gpa, float* __restrict__ gpd,   // [2][64][4096]
    const float* __restrict__ dh,      // f32 dh(t-2)  (for outproj)
    const float* __restrict__ actx,    // [2][64][512] parity (for outproj)
    const float* __restrict__ Wp, const float* __restrict__ bp,
    float* __restrict__ outsOut, int t)
{
  const int q = blockIdx.x, kc = blockIdx.y, z = blockIdx.z;
  const int tid = threadIdx.x;

  __shared__ float part[4][4][16][66];   // [msw][kw][gate*4+r][lane] 67.6 KB

  if (z == 2) {
    // ---- outproj(t-2): out[q][m] for m in [kc*40, kc*40+40) ----
    if (t < 2) return;
    const int bo = q;
    const float* actxR = actx + (size_t)(t & 1) * 32768;   // slot (t-2)&1
    float* cp = (float*)part;
    int mloc = tid / 12, sub = tid - mloc * 12;
    if (tid < 480) {
      int m = kc * 40 + mloc;
      const float4* w4 = (const float4*)(Wp + (size_t)m * 1536 + sub * 128);
      const float4* a4 = (sub < 8)
          ? (const float4*)(dh + (size_t)bo * 1024 + sub * 128)
          : (const float4*)(actxR + (size_t)bo * 512 + (sub - 8) * 128);
      float s = 0.f;
#pragma unroll 8
      for (int kk = 0; kk < 32; kk++) {
        float4 w = w4[kk], av = a4[kk];
        s += w.x * av.x + w.y * av.y + w.z * av.z + w.w * av.w;
      }
      cp[tid] = s;
    }
    __syncthreads();
    if (tid < 40) {
      float acc2 = bp[kc * 40 + tid];
#pragma unroll
      for (int i2 = 0; i2 < 12; i2++) acc2 += cp[tid * 12 + i2];
      outsOut[((size_t)bo * T_OUTT + (t - 2)) * NMEL + kc * 40 + tid] = acc2;
    }
    return;
  }

  const int wv = tid >> 6, lane = tid & 63;
  const int kw = wv & 3, msw = wv >> 2;
  const int mrow = lane & 15, ksub = (lane >> 4) * 8;
  const int row = msw * 16 + mrow;

  f32x4 acc0 = {0.f, 0.f, 0.f, 0.f};
  f32x4 acc1 = acc0, acc2 = acc0, acc3 = acc0;
  float* gp;

  if (z == 0) {
    // ga(t): A = [xs(256) | actx(512) | ah(1024) | pad(256, W=0)], KT=64
    if (t >= T_OUTT) return;
    const size_t gstride = (size_t)64 * 32768;
    const int kt0 = kc * 32 + kw * 8;
    const u16* wb0 = Wa + ((size_t)(q * 64 + kt0) * 64 + lane) * 8;
    const u16* xsb = xs      + (size_t)row * 256  + ksub;
    const u16* axb = actx_bf + (size_t)row * 512  + ksub - 256;
    const u16* ahb = ah_bf   + (size_t)row * 1024 + ksub - 768;
#pragma unroll
    for (int i = 0; i < 8; i++) {
      int kb = (kt0 + i) * 32;
      const u16* ap = (kb < 256) ? (xsb + kb) : ((kb < 768) ? (axb + kb) : (ahb + kb));
      bf16x8 a = ldbf8(ap);
      const u16* wb = wb0 + (size_t)i * 512;
      bf16x8 w0 = ldbf8(wb);
      bf16x8 w1 = ldbf8(wb + gstride);
      bf16x8 w2 = ldbf8(wb + 2 * gstride);
      bf16x8 w3 = ldbf8(wb + 3 * gstride);
      acc0 = __builtin_amdgcn_mfma_f32_16x16x32_bf16(a, w0, acc0, 0, 0, 0);
      acc1 = __builtin_amdgcn_mfma_f32_16x16x32_bf16(a, w1, acc1, 0, 0, 0);
      acc2 = __builtin_amdgcn_mfma_f32_16x16x32_bf16(a, w2, acc2, 0, 0, 0);
      acc3 = __builtin_amdgcn_mfma_f32_16x16x32_bf16(a, w3, acc3, 0, 0, 0);
    }
    gp = gpa;
  } else {
    // gd(t-1): A = [ah(1024) | actx(512) | dh(1024)], KT=80
    if (t < 1 || t > T_OUTT) return;
    const size_t gstride = (size_t)80 * 32768;
    const int kt0 = kc * 40 + kw * 10;
    const u16* wb0 = Wd + ((size_t)(q * 80 + kt0) * 64 + lane) * 8;
    const u16* ahb = ah_bf   + (size_t)row * 1024 + ksub;
    const u16* axb = actx_bf + (size_t)row * 512  + ksub - 1024;
    const u16* dhb = dh_bf   + (size_t)row * 1024 + ksub - 1536;
#pragma unroll
    for (int i = 0; i < 10; i++) {
      int kb = (kt0 + i) * 32;
      const u16* ap = (kb < 1024) ? (ahb + kb) : ((kb < 1536) ? (axb + kb) : (dhb + kb));
      bf16x8 a = ldbf8(ap);
      const u16* wb = wb0 + (size_t)i * 512;
      bf16x8 w0 = ldbf8(wb);
      bf16x8 w1 = ldbf8(wb + gstride);
      bf16x8 w2 = ldbf8(wb + 2 * gstride);
      bf16x8 w3 = ldbf8(wb + 3 * gstride);
      acc0 = __builtin_amdgcn_mfma_f32_16x16x32_bf16(a, w0, acc0, 0, 0, 0);
      acc1 = __builtin_amdgcn_mfma_f32_16x16x32_bf16(a, w1, acc1, 0, 0, 0);
      acc2 = __builtin_amdgcn_mfma_f32_16x16x32_bf16(a, w2, acc2, 0, 0, 0);
      acc3 = __builtin_amdgcn_mfma_f32_16x16x32_bf16(a, w3, acc3, 0, 0, 0);
    }
    gp = gpd;
  }

  // conflict-free partial store (R8 layout, per msw)
#pragma unroll
  for (int r = 0; r < 4; r++) {
    part[msw][kw][r][lane]      = acc0[r];
    part[msw][kw][4 + r][lane]  = acc1[r];
    part[msw][kw][8 + r][lane]  = acc2[r];
    part[msw][kw][12 + r][lane] = acc3[r];
  }
  __syncthreads();
  {
    // 4-way kw reduce + global partial store (R8's proven lane->C mapping)
    int msw2 = tid >> 8, rc = tid & 255, rw = rc >> 4, col = rc & 15;
    int ln = ((rw >> 2) << 4) + col;
    float* dst = gp + ((size_t)(kc * 64 + msw2 * 16 + rw)) * 4096 + q * 16 + col;
#pragma unroll
    for (int g = 0; g < 4; g++) {
      int r = g * 4 + (rw & 3);
      float s = part[msw2][0][r][ln] + part[msw2][1][r][ln]
              + part[msw2][2][r][ln] + part[msw2][3][r][ln];
      dst[(size_t)g * 1024] = s;
    }
  }
}

// ---------------------------------------------------------------------------
// Fused step kernel: 64 blocks (one per batch), __launch_bounds__(1024, 4).
//   (a) activate dh(t-1) from gd partials [t>=1]; ah(t) from ga partials
//       [t<400] -> ahS in LDS directly (no global round-trip for attention)
//   (b) attention(t)  [t<400]
// ---------------------------------------------------------------------------
__global__ __launch_bounds__(1024, 4) void fused_step_kernel(
    const float* __restrict__ gpa, const float* __restrict__ gpd,
    const float* __restrict__ b_a, const float* __restrict__ b_d,
    float* __restrict__ ac, float* __restrict__ dc, float* __restrict__ dh,
    u16* __restrict__ ah_bf, u16* __restrict__ dh_bf,
    float* __restrict__ actx /*[2][64][512]*/, u16* __restrict__ actx_bf,
    float* __restrict__ aw, float* __restrict__ awcum,
    const float* __restrict__ pmT, const float* __restrict__ Wq,
    const float* __restrict__ Wconv, const float* __restrict__ Wloc,
    const float* __restrict__ vvec, const int* __restrict__ lens,
    const float* __restrict__ enc,
    float* __restrict__ alignsOut, int t)
{
  const int b = blockIdx.x, tid = threadIdx.x;
  const int g = tid >> 8, ti = tid & 255;

  __shared__ float2 acS[T_INN];
  __shared__ float ahS[1024];
  __shared__ float pp[128][9];
  __shared__ float pqS[128];
  __shared__ float convS[T_INN][33];
  __shared__ float ep[4][256];
  __shared__ float red[256];
  __shared__ float awS[256];
  __shared__ float cpart[1024];

  const size_t idx = (size_t)b * 1024 + tid;

  // (a) activations (batch-local; gpa/gpd row = batch)
  if (t >= 1) {
    const float* d0 = gpd + (size_t)b * 4096;
    const float* d1 = gpd + (size_t)(64 + b) * 4096;
    float gi = d0[tid]        + d1[tid]        + b_d[tid];
    float gf = d0[tid + 1024] + d1[tid + 1024] + b_d[tid + 1024];
    float gg = d0[tid + 2048] + d1[tid + 2048] + b_d[tid + 2048];
    float go = d0[tid + 3072] + d1[tid + 3072] + b_d[tid + 3072];
    float cn = sigf(gf) * dc[idx] + sigf(gi) * ftanh(gg);
    dc[idx] = cn;
    float hn = sigf(go) * ftanh(cn);
    dh[idx] = hn;
    dh_bf[idx] = f2bf(hn);
  }
  if (t < T_OUTT) {
    const float* a0 = gpa + (size_t)b * 4096;
    const float* a1 = gpa + (size_t)(64 + b) * 4096;
    float gi = a0[tid]        + a1[tid]        + b_a[tid];
    float gf = a0[tid + 1024] + a1[tid + 1024] + b_a[tid + 1024];
    float gg = a0[tid + 2048] + a1[tid + 2048] + b_a[tid + 2048];
    float go = a0[tid + 3072] + a1[tid + 3072] + b_a[tid + 3072];
    float cn = sigf(gf) * ac[idx] + sigf(gi) * ftanh(gg);
    ac[idx] = cn;
    float hn = sigf(go) * ftanh(cn);
    ah_bf[idx] = f2bf(hn);
    ahS[tid] = hn;
  }
  if (t >= T_OUTT) return;

  // (b) attention(t) — R8 body (ahS already populated)
  float* actxW = actx + (size_t)(t & 1) * 32768;
  if (tid < T_INN) {
    float2 v; v.x = aw[b * T_INN + tid]; v.y = awcum[b * T_INN + tid];
    acS[tid] = v;
  }
  __syncthreads();
  {
    int a = tid >> 3, kc = tid & 7;
    const float4* wv = (const float4*)(Wq + (size_t)a * 1024 + kc * 128);
    const float4* hv = (const float4*)(ahS + kc * 128);
    float s = 0.f;
#pragma unroll 8
    for (int i = 0; i < 32; i++) {
      float4 wq = wv[i], hh = hv[i];
      s += wq.x * hh.x + wq.y * hh.y + wq.z * hh.z + wq.w * hh.w;
    }
    pp[a][kc] = s;
  }
  __syncthreads();
  if (tid < 128) {
    float s = 0.f;
#pragma unroll
    for (int kc = 0; kc < 8; kc++) s += pp[tid][kc];
    pqS[tid] = s;
  }
  if (ti < T_INN) {
    float sacc[8] = {0.f, 0.f, 0.f, 0.f, 0.f, 0.f, 0.f, 0.f};
#pragma unroll
    for (int k = 0; k < 31; k++) {
      int tt = ti + k - 15;
      if (tt >= 0 && tt < T_INN) {
        float2 v = acS[tt];
#pragma unroll
        for (int f8 = 0; f8 < 8; f8++) {
          int f = g * 8 + f8;
          sacc[f8] += Wconv[f * 62 + k] * v.x + Wconv[f * 62 + 31 + k] * v.y;
        }
      }
    }
#pragma unroll
    for (int f8 = 0; f8 < 8; f8++) convS[ti][g * 8 + f8] = sacc[f8];
  }
  __syncthreads();
  float e = 0.f;
  if (ti < T_INN) {
    float cv[32];
#pragma unroll
    for (int f = 0; f < 32; f++) cv[f] = convS[ti][f];
    const float* pm = pmT + ((size_t)b * 128 + g * 32) * T_INN + ti;
#pragma unroll 4
    for (int aa = 0; aa < 32; aa++) {
      int a = g * 32 + aa;
      float x = pqS[a] + pm[(size_t)aa * T_INN];
      const float* wl = Wloc + a * 32;
#pragma unroll
      for (int f = 0; f < 32; f++) x += wl[f] * cv[f];
      float ex2 = __expf(2.f * x);
      e += vvec[a] * (1.f - 2.f * __builtin_amdgcn_rcpf(ex2 + 1.f));
    }
  }
  ep[g][ti] = e;
  __syncthreads();
  float ev = -3.0e38f, ex = 0.f;
  if (tid < 256) {
    if (tid < T_INN) {
      ev = ep[0][tid] + ep[1][tid] + ep[2][tid] + ep[3][tid];
      if (tid >= lens[b]) ev = -100000000.0f;
    }
    red[tid] = ev;
  }
  __syncthreads();
  for (int s2 = 128; s2 > 0; s2 >>= 1) {
    if (tid < s2) red[tid] = fmaxf(red[tid], red[tid + s2]);
    __syncthreads();
  }
  float mx = red[0];
  __syncthreads();
  if (tid < 256) { ex = (tid < T_INN) ? __expf(ev - mx) : 0.f; red[tid] = ex; }
  __syncthreads();
  for (int s2 = 128; s2 > 0; s2 >>= 1) {
    if (tid < s2) red[tid] += red[tid + s2];
    __syncthreads();
  }
  float inv = 1.0f / red[0];
  if (tid < T_INN) {
    float a = ex * inv;
    awS[tid] = a;
    aw[b * T_INN + tid] = a;
    awcum[b * T_INN + tid] = acS[tid].y + a;
    alignsOut[((size_t)b * T_OUTT + t) * T_INN + tid] = a;
  }
  __syncthreads();
  {
    int e0 = tid & 511, half = tid >> 9;
    const float* ep2 = enc + ((size_t)b * T_INN + half * 100) * DENC + e0;
    float s = 0.f;
#pragma unroll 4
    for (int tt = 0; tt < 100; tt++) s += awS[half * 100 + tt] * ep2[(size_t)tt * DENC];
    cpart[tid] = s;
  }
  __syncthreads();
  if (tid < 512) {
    float v2 = cpart[tid] + cpart[512 + tid];
    actxW[b * DENC + tid] = v2;
    actx_bf[b * DENC + tid] = f2bf(v2);
  }
}

extern "C" void kernel_launch(void* const* d_in, const int* in_sizes, int n_in,
                              void* d_out, int out_size, void* d_ws, size_t ws_size,
                              hipStream_t stream)
{
  const float* enc    = (const float*)d_in[0];
  const float* dec    = (const float*)d_in[1];
  const int*   lens   = (const int*)d_in[2];
  const float* W_p1   = (const float*)d_in[3];
  const float* W_p2   = (const float*)d_in[4];
  const float* W_ih_a = (const float*)d_in[5];
  const float* W_hh_a = (const float*)d_in[6];
  const float* b_a    = (const float*)d_in[7];
  const float* Wq     = (const float*)d_in[8];
  const float* Wmem   = (const float*)d_in[9];
  const float* vvec   = (const float*)d_in[10];
  const float* Wconv  = (const float*)d_in[11];
  const float* Wloc   = (const float*)d_in[12];
  const float* W_ih_d = (const float*)d_in[13];
  const float* W_hh_d = (const float*)d_in[14];
  const float* b_d    = (const float*)d_in[15];
  const float* Wp     = (const float*)d_in[16];
  const float* bp     = (const float*)d_in[17];

  float* ws = (float*)d_ws;
  size_t off = 0;
  u16* xs_bf = (u16*)(ws + off); off += (size_t)T_OUTT * 64 * 256 / 2;
  float* pmT = ws + off; off += (size_t)64 * 128 * T_INN;
  u16* Wa_pack = (u16*)(ws + off); off += (size_t)4096 * 2048 / 2;   // KT=64 padded
  u16* Wd_pack = (u16*)(ws + off); off += (size_t)4096 * 2560 / 2;   // KT=80
  // state block (zero-initialized)
  float* stateBase = ws + off;
  float* dh    = stateBase;            // f32 [64][1024]
  float* ac    = dh + 65536;
  float* dc    = ac + 65536;
  float* actx  = dc + 65536;           // [2][64][512] parity
  float* aw    = actx + 2 * 32768;
  float* awcum = aw + 12800;
  u16* ah_bf   = (u16*)(awcum + 12800);     // [64][1024] single copy
  u16* dh_bf   = ah_bf + 65536;             // [64][1024] single copy
  u16* actx_bf = dh_bf + 65536;             // [64][512]  single copy
  size_t stateFloats = 3 * 65536 + 2 * 32768 + 2 * 12800
                     + (65536 + 65536 + 32768) / 2;
  off += stateFloats;
  float* scratch = ws + off;           // precompute h1/pmt; decode: gpa/gpd
  float* h1 = scratch;                 // 399*64 x 256
  float* pmt = scratch;                // reused after prenet
  float* gpa = scratch;                // [2][64][4096] f32 = 2 MB
  float* gpd = scratch + (size_t)2 * 64 * 4096;

  float* outsOut   = (float*)d_out;
  float* alignsOut = outsOut + (size_t)BB * T_OUTT * NMEL;

  // zero recurrent state + t=0 prenet row; zero Wa_pack (KT padding)
  hipMemsetAsync(stateBase, 0, stateFloats * sizeof(float), stream);
  hipMemsetAsync(xs_bf, 0, (size_t)64 * 256 * sizeof(u16), stream);
  hipMemsetAsync(Wa_pack, 0, (size_t)4096 * 2048 * sizeof(u16), stream);

  // ---- precompute ----
  {
    int tot;
    tot = 256 * 24 * 64;
    pack_w_kernel<<<(tot + 255) / 256, 256, 0, stream>>>(W_ih_a, Wa_pack, 768, 24, 0, 64, tot);
    tot = 256 * 32 * 64;
    pack_w_kernel<<<(tot + 255) / 256, 256, 0, stream>>>(W_hh_a, Wa_pack, 1024, 32, 24, 64, tot);
    tot = 256 * 48 * 64;
    pack_w_kernel<<<(tot + 255) / 256, 256, 0, stream>>>(W_ih_d, Wd_pack, 1536, 48, 0, 80, tot);
    tot = 256 * 32 * 64;
    pack_w_kernel<<<(tot + 255) / 256, 256, 0, stream>>>(W_hh_d, Wd_pack, 1024, 32, 48, 80, tot);
  }
  gemm_pre_kernel<<<dim3(4, 399), 256, 0, stream>>>(dec, 80, W_p1, 80, h1, nullptr, 256, 80, 1);
  gemm_pre_kernel<<<dim3(4, 399), 256, 0, stream>>>(h1, 256, W_p2, 256, nullptr, xs_bf + 64 * 256, 256, 256, 1);
  gemm_pre_kernel<<<dim3(2, 200), 256, 0, stream>>>(enc, 512, Wmem, 512, pmt, nullptr, 128, 512, 0);
  transpose_pm_kernel<<<dim3(7, 4, 64), dim3(32, 8), 0, stream>>>(pmt, pmT);

  // ---- decode loop: 2 dispatches per step ----
  // gates(t): z0 ga(t) partial; z1 gd(t-1) partial; z2 outproj(t-2)
  // fused(t): activate dh(t-1), ah(t); attention(t)
  for (int t = 0; t <= T_OUTT + 1; t++) {
    int tc = (t < T_OUTT) ? t : 0;
    gates_kernel<<<dim3(64, 2, 3), 1024, 0, stream>>>(
        xs_bf + (size_t)tc * 64 * 256, actx_bf, ah_bf, dh_bf,
        Wa_pack, Wd_pack, gpa, gpd, dh, actx, Wp, bp, outsOut, t);
    if (t <= T_OUTT)
      fused_step_kernel<<<64, 1024, 0, stream>>>(
          gpa, gpd, b_a, b_d, ac, dc, dh, ah_bf, dh_bf, actx, actx_bf,
          aw, awcum, pmT, Wq, Wconv, Wloc, vvec, lens, enc, alignsOut, t);
  }
}

// Round 11
// 33818.298 us; speedup vs baseline: 2.1373x; 1.1656x over previous
//
#include <hip/hip_runtime.h>
#include <cstddef>
#include <cstdint>

#define T_INN 200
#define T_OUTT 400
#define BB 64
#define DENC 512
#define NMEL 80

typedef unsigned short u16;
typedef __bf16 bf16x8 __attribute__((ext_vector_type(8)));
typedef float f32x4 __attribute__((ext_vector_type(4)));

// fast sigmoid/tanh (validated R5-R8: absmax unchanged at 0.00098)
__device__ __forceinline__ float sigf(float x) {
  return __builtin_amdgcn_rcpf(1.0f + __expf(-x));
}
__device__ __forceinline__ float ftanh(float x) {
  float e2 = __expf(2.0f * x);
  return 1.0f - 2.0f * __builtin_amdgcn_rcpf(e2 + 1.0f);
}

// round-to-nearest-even f32 -> bf16
__device__ __forceinline__ u16 f2bf(float f) {
  unsigned u = __float_as_uint(f);
  unsigned r = u + 0x7fffu + ((u >> 16) & 1u);
  return (u16)(r >> 16);
}

__device__ __forceinline__ bf16x8 ldbf8(const u16* p) { return *(const bf16x8*)p; }

// ---------------------------------------------------------------------------
// fp32 tiled GEMM for precompute: C[m][n] = act(sum_k A[m][k]*W[n][k])
// ---------------------------------------------------------------------------
__global__ __launch_bounds__(256) void gemm_pre_kernel(
    const float* __restrict__ A, int lda, const float* __restrict__ W, int ldw,
    float* __restrict__ C, u16* __restrict__ Cbf, int ldc, int K, int relu)
{
  __shared__ float As[16][66];
  __shared__ float Ws[16][66];
  const int tid = threadIdx.x;
  const int tn = tid & 15, tm = tid >> 4;
  const int n0 = blockIdx.x * 64;
  const int m0 = blockIdx.y * 64;
  float acc[4][4] = {{0.f}};
  for (int kt = 0; kt < K; kt += 16) {
#pragma unroll
    for (int i = 0; i < 4; i++) {
      int e = tid + 256 * i;
      int m = e >> 4, kk = e & 15;
      As[kk][m] = A[(size_t)(m0 + m) * lda + kt + kk];
    }
#pragma unroll
    for (int i = 0; i < 4; i++) {
      int e = tid + 256 * i;
      int n = e >> 4, kk = e & 15;
      Ws[kk][n] = W[(size_t)(n0 + n) * ldw + kt + kk];
    }
    __syncthreads();
#pragma unroll
    for (int kk = 0; kk < 16; kk++) {
      float2 a01 = *(const float2*)&As[kk][tm * 4];
      float2 a23 = *(const float2*)&As[kk][tm * 4 + 2];
      float2 w01 = *(const float2*)&Ws[kk][tn * 4];
      float2 w23 = *(const float2*)&Ws[kk][tn * 4 + 2];
      float a[4] = {a01.x, a01.y, a23.x, a23.y};
      float w[4] = {w01.x, w01.y, w23.x, w23.y};
#pragma unroll
      for (int mi = 0; mi < 4; mi++)
#pragma unroll
        for (int ni = 0; ni < 4; ni++)
          acc[mi][ni] = fmaf(a[mi], w[ni], acc[mi][ni]);
    }
    __syncthreads();
  }
#pragma unroll
  for (int mi = 0; mi < 4; mi++) {
    int m = m0 + tm * 4 + mi;
    float v0 = acc[mi][0], v1 = acc[mi][1], v2 = acc[mi][2], v3 = acc[mi][3];
    if (relu) {
      v0 = fmaxf(v0, 0.f); v1 = fmaxf(v1, 0.f);
      v2 = fmaxf(v2, 0.f); v3 = fmaxf(v3, 0.f);
    }
    if (Cbf) {
      u16* p = Cbf + (size_t)m * ldc + n0 + tn * 4;
      p[0] = f2bf(v0); p[1] = f2bf(v1); p[2] = f2bf(v2); p[3] = f2bf(v3);
    } else {
      float4 vv; vv.x = v0; vv.y = v1; vv.z = v2; vv.w = v3;
      *(float4*)&C[(size_t)m * ldc + n0 + tn * 4] = vv;
    }
  }
}

// ---------------------------------------------------------------------------
// Weight repack: W[n][k] fp32 -> bf16, MFMA B-fragment lane order.
// ---------------------------------------------------------------------------
__global__ __launch_bounds__(256) void pack_w_kernel(
    const float* __restrict__ W, u16* __restrict__ P,
    int K, int KTl, int ktOff, int KTtot, int total)
{
  int slot = blockIdx.x * 256 + threadIdx.x;
  if (slot >= total) return;
  int lane = slot & 63;
  int ktl = (slot >> 6) % KTl;
  int nt = slot / (64 * KTl);
  int n = nt * 16 + (lane & 15);
  int k = ktl * 32 + (lane >> 4) * 8;
  const float* src = W + (size_t)n * K + k;
  u16 tmp[8];
#pragma unroll
  for (int i = 0; i < 8; i++) tmp[i] = f2bf(src[i]);
  u16* dst = P + ((size_t)(nt * KTtot + (ktl + ktOff)) * 64 + lane) * 8;
  *(uint4*)dst = *(const uint4*)tmp;
}

// pm (b*t, a) -> pmT (b, a, t)
__global__ void transpose_pm_kernel(const float* __restrict__ pm, float* __restrict__ pmT)
{
  int b = blockIdx.z;
  int tT = blockIdx.x * 32, aT = blockIdx.y * 32;
  __shared__ float tile[32][33];
  int tx = threadIdx.x, ty = threadIdx.y;
#pragma unroll
  for (int i = 0; i < 4; i++) {
    int t = tT + ty + i * 8;
    int a = aT + tx;
    if (t < T_INN) tile[ty + i * 8][tx] = pm[((size_t)b * T_INN + t) * 128 + a];
  }
  __syncthreads();
#pragma unroll
  for (int i = 0; i < 4; i++) {
    int a = aT + ty + i * 8;
    int t = tT + tx;
    if (t < T_INN) pmT[((size_t)b * 128 + a) * T_INN + t] = tile[tx][ty + i * 8];
  }
}

// ---------------------------------------------------------------------------
// Gates + LSTM activation, full-K per block. grid (64 quads, 2 m-pairs, 2
// gate-types), 1024 threads (16 waves, split-K over waves, LDS reduce).
// WEIGHT DEDUP vs R8: each block now covers 32 rows (2 m-slices). Each wave
// loads the weight fragments ONCE and issues 8 MFMA (lo rows + hi rows):
// weight traffic per step halves (151 -> 76 MB) with no new round-trips.
// z=0: gatesA(t) KT=64 (zero-padded from 56); z=1: gatesD(t-1) KT=80.
// ---------------------------------------------------------------------------
struct SmemGates {
  float part[16][16][66];   // [kw][gate*4+reg][lane(+pad)] conflict-free
  float gred[1024];
};

__global__ __launch_bounds__(1024, 4) void gates_kernel(
    const u16* __restrict__ xs,        // [64][256] prenet rows for step t
    const u16* __restrict__ actx_bf,   // [64][512]
    const u16* __restrict__ ah_bf_r, u16* __restrict__ ah_bf_w,
    const u16* __restrict__ dh_bf_r, u16* __restrict__ dh_bf_w,
    const u16* __restrict__ Wa, const u16* __restrict__ Wd,
    const float* __restrict__ b_a, const float* __restrict__ b_d,
    float* __restrict__ ah, float* __restrict__ ac,
    float* __restrict__ dh, float* __restrict__ dc, int t)
{
  const int z = blockIdx.z;
  if (z == 0 && t >= T_OUTT) return;
  if (z == 1 && t < 1) return;
  const int bq = blockIdx.x, ms2 = blockIdx.y;   // rows ms2*32 .. ms2*32+31
  const int tid = threadIdx.x;
  const int kw = tid >> 6, lane = tid & 63;
  const int mrow = lane & 15, ksub = (lane >> 4) * 8;
  const int rowL = ms2 * 32 + mrow;
  const int rowH = rowL + 16;
  __shared__ SmemGates sg;

  f32x4 zero4 = {0.f, 0.f, 0.f, 0.f};
  f32x4 aL0 = zero4, aL1 = zero4, aL2 = zero4, aL3 = zero4;
  f32x4 aH0 = zero4, aH1 = zero4, aH2 = zero4, aH3 = zero4;
  const float* bias; float* hF; float* cSt; u16* hw;

  if (z == 0) {
    // gatesA(t): A = [xs(256) | actx(512) | ah(1024) | pad(256, W=0)], KT=64
    constexpr int KT = 64;
    const size_t gstride = (size_t)KT * 32768;
    const u16* wb0 = Wa + ((size_t)(bq * KT + kw * 4) * 64 + lane) * 8;
    // contiguous chunk kt = kw*4 + i ; segment is a wave-uniform fn of kw
    const u16* rbL; const u16* rbH;
    if (kw < 2) {
      rbL = xs + (size_t)rowL * 256 + ksub + kw * 128;
      rbH = xs + (size_t)rowH * 256 + ksub + kw * 128;
    } else if (kw < 6) {
      rbL = actx_bf + (size_t)rowL * 512 + ksub + kw * 128 - 256;
      rbH = actx_bf + (size_t)rowH * 512 + ksub + kw * 128 - 256;
    } else {
      rbL = ah_bf_r + (size_t)rowL * 1024 + ksub + kw * 128 - 768;
      rbH = ah_bf_r + (size_t)rowH * 1024 + ksub + kw * 128 - 768;
    }
#pragma unroll
    for (int i = 0; i < 4; i++) {
      bf16x8 al = ldbf8(rbL + i * 32);
      bf16x8 ahi = ldbf8(rbH + i * 32);
      const u16* wb = wb0 + (size_t)i * 512;
      bf16x8 w0 = ldbf8(wb);
      bf16x8 w1 = ldbf8(wb + gstride);
      bf16x8 w2 = ldbf8(wb + 2 * gstride);
      bf16x8 w3 = ldbf8(wb + 3 * gstride);
      aL0 = __builtin_amdgcn_mfma_f32_16x16x32_bf16(al, w0, aL0, 0, 0, 0);
      aL1 = __builtin_amdgcn_mfma_f32_16x16x32_bf16(al, w1, aL1, 0, 0, 0);
      aL2 = __builtin_amdgcn_mfma_f32_16x16x32_bf16(al, w2, aL2, 0, 0, 0);
      aL3 = __builtin_amdgcn_mfma_f32_16x16x32_bf16(al, w3, aL3, 0, 0, 0);
      aH0 = __builtin_amdgcn_mfma_f32_16x16x32_bf16(ahi, w0, aH0, 0, 0, 0);
      aH1 = __builtin_amdgcn_mfma_f32_16x16x32_bf16(ahi, w1, aH1, 0, 0, 0);
      aH2 = __builtin_amdgcn_mfma_f32_16x16x32_bf16(ahi, w2, aH2, 0, 0, 0);
      aH3 = __builtin_amdgcn_mfma_f32_16x16x32_bf16(ahi, w3, aH3, 0, 0, 0);
    }
    bias = b_a; hF = ah; cSt = ac; hw = ah_bf_w;
  } else {
    // gatesD(t-1): A = [ah(1024) | actx(512) | dh(1024)], KT=80
    constexpr int KT = 80;
    const size_t gstride = (size_t)KT * 32768;
    const u16* wb0 = Wd + ((size_t)(bq * KT + kw) * 64 + lane) * 8;
    // interleaved chunk kt = kw + 16*i ; segment is a compile-time fn of i
    const u16* a0L = ah_bf_r + (size_t)rowL * 1024 + ksub + kw * 32;
    const u16* a1L = actx_bf + (size_t)rowL * 512  + ksub + kw * 32;
    const u16* a2L = dh_bf_r + (size_t)rowL * 1024 + ksub + kw * 32;
    const u16* a0H = ah_bf_r + (size_t)rowH * 1024 + ksub + kw * 32;
    const u16* a1H = actx_bf + (size_t)rowH * 512  + ksub + kw * 32;
    const u16* a2H = dh_bf_r + (size_t)rowH * 1024 + ksub + kw * 32;
#pragma unroll
    for (int i = 0; i < 5; i++) {
      const u16* apL = (i < 2) ? (a0L + i * 512) : ((i == 2) ? a1L : (a2L + (i - 3) * 512));
      const u16* apH = (i < 2) ? (a0H + i * 512) : ((i == 2) ? a1H : (a2H + (i - 3) * 512));
      bf16x8 al = ldbf8(apL);
      bf16x8 ahi = ldbf8(apH);
      const u16* wb = wb0 + (size_t)i * (16 * 512);
      bf16x8 w0 = ldbf8(wb);
      bf16x8 w1 = ldbf8(wb + gstride);
      bf16x8 w2 = ldbf8(wb + 2 * gstride);
      bf16x8 w3 = ldbf8(wb + 3 * gstride);
      aL0 = __builtin_amdgcn_mfma_f32_16x16x32_bf16(al, w0, aL0, 0, 0, 0);
      aL1 = __builtin_amdgcn_mfma_f32_16x16x32_bf16(al, w1, aL1, 0, 0, 0);
      aL2 = __builtin_amdgcn_mfma_f32_16x16x32_bf16(al, w2, aL2, 0, 0, 0);
      aL3 = __builtin_amdgcn_mfma_f32_16x16x32_bf16(al, w3, aL3, 0, 0, 0);
      aH0 = __builtin_amdgcn_mfma_f32_16x16x32_bf16(ahi, w0, aH0, 0, 0, 0);
      aH1 = __builtin_amdgcn_mfma_f32_16x16x32_bf16(ahi, w1, aH1, 0, 0, 0);
      aH2 = __builtin_amdgcn_mfma_f32_16x16x32_bf16(ahi, w2, aH2, 0, 0, 0);
      aH3 = __builtin_amdgcn_mfma_f32_16x16x32_bf16(ahi, w3, aH3, 0, 0, 0);
    }
    bias = b_d; hF = dh; cSt = dc; hw = dh_bf_w;
  }

  // epilogue twice (lo rows, hi rows), reusing the same LDS buffer
#pragma unroll
  for (int h = 0; h < 2; h++) {
    if (h == 1) __syncthreads();   // reduce-read of pass 0 done before overwrite
#pragma unroll
    for (int r = 0; r < 4; r++) {
      if (h == 0) {
        sg.part[kw][r][lane]      = aL0[r];
        sg.part[kw][4 + r][lane]  = aL1[r];
        sg.part[kw][8 + r][lane]  = aL2[r];
        sg.part[kw][12 + r][lane] = aL3[r];
      } else {
        sg.part[kw][r][lane]      = aH0[r];
        sg.part[kw][4 + r][lane]  = aH1[r];
        sg.part[kw][8 + r][lane]  = aH2[r];
        sg.part[kw][12 + r][lane] = aH3[r];
      }
    }
    __syncthreads();
    {
      int g = tid >> 8, rc = tid & 255, rw = rc >> 4, col = rc & 15;
      int ln = ((rw >> 2) << 4) + col;
      int r = g * 4 + (rw & 3);
      float s = 0.f;
#pragma unroll
      for (int k2 = 0; k2 < 16; k2++) s += sg.part[k2][r][ln];
      sg.gred[tid] = s;
    }
    __syncthreads();
    if (tid < 256) {
      int rw = tid >> 4, col = tid & 15;
      int j = bq * 16 + col, m = ms2 * 32 + h * 16 + rw;
      size_t idx = (size_t)m * 1024 + j;
      float gi = sg.gred[tid]       + bias[j];
      float gf = sg.gred[256 + tid] + bias[j + 1024];
      float gg = sg.gred[512 + tid] + bias[j + 2048];
      float go = sg.gred[768 + tid] + bias[j + 3072];
      float cn = sigf(gf) * cSt[idx] + sigf(gi) * ftanh(gg);
      cSt[idx] = cn;
      float hn = sigf(go) * ftanh(cn);
      hF[idx] = hn;
      hw[idx] = f2bf(hn);
    }
  }
}

// ---------------------------------------------------------------------------
// Fused step kernel (R8 verbatim): grid 128, __launch_bounds__(1024, 4).
//   b in [0,64):   attention(t) for batch b        [skip t==400]
//   b in [64,128): outproj(t-1) for batch b-64     [skip t==0]
// ---------------------------------------------------------------------------
__global__ __launch_bounds__(1024, 4) void fused_step_kernel(
    const float* __restrict__ ah, const float* __restrict__ dh,
    float* __restrict__ actx /*[2][64][512]*/, u16* __restrict__ actx_bf,
    float* __restrict__ aw, float* __restrict__ awcum,
    const float* __restrict__ pmT, const float* __restrict__ Wq,
    const float* __restrict__ Wconv, const float* __restrict__ Wloc,
    const float* __restrict__ vvec, const int* __restrict__ lens,
    const float* __restrict__ enc, const float* __restrict__ Wp,
    const float* __restrict__ bp,
    float* __restrict__ outsOut, float* __restrict__ alignsOut, int t)
{
  const int tid = threadIdx.x;

  if (blockIdx.x >= 64) {
    // ---- outproj(t-1) ----
    if (t < 1) return;
    const int bo = blockIdx.x - 64;
    const float* actxR = actx + (size_t)((t - 1) & 1) * 32768;
    __shared__ float cp[1024];
    float s = 0.f;
    int m = tid / 12, sub = tid - m * 12;
    if (tid < 960) {
      const float4* w4 = (const float4*)(Wp + (size_t)m * 1536 + sub * 128);
      const float4* a4 = (sub < 8)
          ? (const float4*)(dh + (size_t)bo * 1024 + sub * 128)
          : (const float4*)(actxR + (size_t)bo * 512 + (sub - 8) * 128);
#pragma unroll 8
      for (int kk = 0; kk < 32; kk++) {
        float4 w = w4[kk], av = a4[kk];
        s += w.x * av.x + w.y * av.y + w.z * av.z + w.w * av.w;
      }
    }
    cp[tid] = s;
    __syncthreads();
    if (tid < 80) {
      float acc2 = bp[tid];
#pragma unroll
      for (int i2 = 0; i2 < 12; i2++) acc2 += cp[tid * 12 + i2];
      outsOut[((size_t)bo * T_OUTT + (t - 1)) * NMEL + tid] = acc2;
    }
    return;
  }

  // ---- attention(t) ----
  if (t >= T_OUTT) return;
  const int b = blockIdx.x;
  const int g = tid >> 8, ti = tid & 255;
  float* actxW = actx + (size_t)(t & 1) * 32768;

  __shared__ float2 acS[T_INN];        // (aw, awcum) merged -> ds_read_b64
  __shared__ float ahS[1024];
  __shared__ float pp[128][9];
  __shared__ float pqS[128];
  __shared__ float convS[T_INN][33];
  __shared__ float ep[4][256];
  __shared__ float red[256];
  __shared__ float awS[256];
  __shared__ float cpart[1024];

  if (tid < T_INN) {
    float2 v; v.x = aw[b * T_INN + tid]; v.y = awcum[b * T_INN + tid];
    acS[tid] = v;
  }
  ahS[tid] = ah[(size_t)b * 1024 + tid];
  __syncthreads();
  {
    int a = tid >> 3, kc = tid & 7;
    const float4* wv = (const float4*)(Wq + (size_t)a * 1024 + kc * 128);
    const float4* hv = (const float4*)(ahS + kc * 128);
    float s = 0.f;
#pragma unroll 8
    for (int i = 0; i < 32; i++) {
      float4 wq = wv[i], hh = hv[i];
      s += wq.x * hh.x + wq.y * hh.y + wq.z * hh.z + wq.w * hh.w;
    }
    pp[a][kc] = s;
  }
  __syncthreads();
  if (tid < 128) {
    float s = 0.f;
#pragma unroll
    for (int kc = 0; kc < 8; kc++) s += pp[tid][kc];
    pqS[tid] = s;
  }
  if (ti < T_INN) {
    // conv, k-outer: window element read ONCE (float2), 8 reg accumulators
    float sacc[8] = {0.f, 0.f, 0.f, 0.f, 0.f, 0.f, 0.f, 0.f};
#pragma unroll
    for (int k = 0; k < 31; k++) {
      int tt = ti + k - 15;
      if (tt >= 0 && tt < T_INN) {
        float2 v = acS[tt];
#pragma unroll
        for (int f8 = 0; f8 < 8; f8++) {
          int f = g * 8 + f8;
          sacc[f8] += Wconv[f * 62 + k] * v.x + Wconv[f * 62 + 31 + k] * v.y;
        }
      }
    }
#pragma unroll
    for (int f8 = 0; f8 < 8; f8++) convS[ti][g * 8 + f8] = sacc[f8];
  }
  __syncthreads();
  float e = 0.f;
  if (ti < T_INN) {
    // energies: convS row hoisted once (32 regs), then pure-VALU loop
    float cv[32];
#pragma unroll
    for (int f = 0; f < 32; f++) cv[f] = convS[ti][f];
    const float* pm = pmT + ((size_t)b * 128 + g * 32) * T_INN + ti;
#pragma unroll 4
    for (int aa = 0; aa < 32; aa++) {
      int a = g * 32 + aa;
      float x = pqS[a] + pm[(size_t)aa * T_INN];
      const float* wl = Wloc + a * 32;
#pragma unroll
      for (int f = 0; f < 32; f++) x += wl[f] * cv[f];
      float ex2 = __expf(2.f * x);
      e += vvec[a] * (1.f - 2.f * __builtin_amdgcn_rcpf(ex2 + 1.f));
    }
  }
  ep[g][ti] = e;
  __syncthreads();
  float ev = -3.0e38f, ex = 0.f;
  if (tid < 256) {
    if (tid < T_INN) {
      ev = ep[0][tid] + ep[1][tid] + ep[2][tid] + ep[3][tid];
      if (tid >= lens[b]) ev = -100000000.0f;
    }
    red[tid] = ev;
  }
  __syncthreads();
  for (int s2 = 128; s2 > 0; s2 >>= 1) {
    if (tid < s2) red[tid] = fmaxf(red[tid], red[tid + s2]);
    __syncthreads();
  }
  float mx = red[0];
  __syncthreads();
  if (tid < 256) { ex = (tid < T_INN) ? __expf(ev - mx) : 0.f; red[tid] = ex; }
  __syncthreads();
  for (int s2 = 128; s2 > 0; s2 >>= 1) {
    if (tid < s2) red[tid] += red[tid + s2];
    __syncthreads();
  }
  float inv = 1.0f / red[0];
  if (tid < T_INN) {
    float a = ex * inv;
    awS[tid] = a;
    aw[b * T_INN + tid] = a;
    awcum[b * T_INN + tid] = acS[tid].y + a;
    alignsOut[((size_t)b * T_OUTT + t) * T_INN + tid] = a;
  }
  __syncthreads();
  {
    int e0 = tid & 511, half = tid >> 9;
    const float* ep2 = enc + ((size_t)b * T_INN + half * 100) * DENC + e0;
    float s = 0.f;
#pragma unroll 4
    for (int tt = 0; tt < 100; tt++) s += awS[half * 100 + tt] * ep2[(size_t)tt * DENC];
    cpart[tid] = s;
  }
  __syncthreads();
  if (tid < 512) {
    float v2 = cpart[tid] + cpart[512 + tid];
    actxW[b * DENC + tid] = v2;
    actx_bf[b * DENC + tid] = f2bf(v2);
  }
}

extern "C" void kernel_launch(void* const* d_in, const int* in_sizes, int n_in,
                              void* d_out, int out_size, void* d_ws, size_t ws_size,
                              hipStream_t stream)
{
  const float* enc    = (const float*)d_in[0];
  const float* dec    = (const float*)d_in[1];
  const int*   lens   = (const int*)d_in[2];
  const float* W_p1   = (const float*)d_in[3];
  const float* W_p2   = (const float*)d_in[4];
  const float* W_ih_a = (const float*)d_in[5];
  const float* W_hh_a = (const float*)d_in[6];
  const float* b_a    = (const float*)d_in[7];
  const float* Wq     = (const float*)d_in[8];
  const float* Wmem   = (const float*)d_in[9];
  const float* vvec   = (const float*)d_in[10];
  const float* Wconv  = (const float*)d_in[11];
  const float* Wloc   = (const float*)d_in[12];
  const float* W_ih_d = (const float*)d_in[13];
  const float* W_hh_d = (const float*)d_in[14];
  const float* b_d    = (const float*)d_in[15];
  const float* Wp     = (const float*)d_in[16];
  const float* bp     = (const float*)d_in[17];

  float* ws = (float*)d_ws;
  size_t off = 0;
  u16* xs_bf = (u16*)(ws + off); off += (size_t)T_OUTT * 64 * 256 / 2;
  float* pmT = ws + off; off += (size_t)64 * 128 * T_INN;
  u16* Wa_pack = (u16*)(ws + off); off += (size_t)4096 * 2048 / 2;   // KT=64 padded
  u16* Wd_pack = (u16*)(ws + off); off += (size_t)4096 * 2560 / 2;   // KT=80
  // state block (zero-initialized)
  float* stateBase = ws + off;
  float* ah    = stateBase;            // f32 [64][1024]
  float* dh    = ah + 65536;
  float* ac    = dh + 65536;
  float* dc    = ac + 65536;
  float* actx  = dc + 65536;           // [2][64][512] parity
  float* aw    = actx + 2 * 32768;
  float* awcum = aw + 12800;
  u16* ah_bf   = (u16*)(awcum + 12800);     // [2][64][1024]
  u16* dh_bf   = ah_bf + 2 * 65536;         // [2][64][1024]
  u16* actx_bf = dh_bf + 2 * 65536;         // [64][512]
  size_t stateFloats = 4 * 65536 + 2 * 32768 + 2 * 12800
                     + (2 * 65536 + 2 * 65536 + 32768) / 2;
  off += stateFloats;
  float* scratch = ws + off;           // precompute only
  float* h1 = scratch;                 // 399*64 x 256
  float* pmt = scratch;                // reused after prenet

  float* outsOut   = (float*)d_out;
  float* alignsOut = outsOut + (size_t)BB * T_OUTT * NMEL;

  // zero recurrent state + t=0 prenet row; zero Wa_pack (KT padding)
  hipMemsetAsync(stateBase, 0, stateFloats * sizeof(float), stream);
  hipMemsetAsync(xs_bf, 0, (size_t)64 * 256 * sizeof(u16), stream);
  hipMemsetAsync(Wa_pack, 0, (size_t)4096 * 2048 * sizeof(u16), stream);

  // ---- precompute ----
  {
    int tot;
    tot = 256 * 24 * 64;
    pack_w_kernel<<<(tot + 255) / 256, 256, 0, stream>>>(W_ih_a, Wa_pack, 768, 24, 0, 64, tot);
    tot = 256 * 32 * 64;
    pack_w_kernel<<<(tot + 255) / 256, 256, 0, stream>>>(W_hh_a, Wa_pack, 1024, 32, 24, 64, tot);
    tot = 256 * 48 * 64;
    pack_w_kernel<<<(tot + 255) / 256, 256, 0, stream>>>(W_ih_d, Wd_pack, 1536, 48, 0, 80, tot);
    tot = 256 * 32 * 64;
    pack_w_kernel<<<(tot + 255) / 256, 256, 0, stream>>>(W_hh_d, Wd_pack, 1024, 32, 48, 80, tot);
  }
  gemm_pre_kernel<<<dim3(4, 399), 256, 0, stream>>>(dec, 80, W_p1, 80, h1, nullptr, 256, 80, 1);
  gemm_pre_kernel<<<dim3(4, 399), 256, 0, stream>>>(h1, 256, W_p2, 256, nullptr, xs_bf + 64 * 256, 256, 256, 1);
  gemm_pre_kernel<<<dim3(2, 200), 256, 0, stream>>>(enc, 512, Wmem, 512, pmt, nullptr, 128, 512, 0);
  transpose_pm_kernel<<<dim3(7, 4, 64), dim3(32, 8), 0, stream>>>(pmt, pmT);

  // ---- decode loop: 2 dispatches per step ----
  // parity: at step t, gatesA writes ah_bf[t&1], reads ah_bf[(t+1)&1];
  //         gatesD (computes dh(t-1)) reads dh_bf[t&1], writes dh_bf[(t+1)&1].
  for (int t = 0; t <= T_OUTT; t++) {
    int tc = (t < T_OUTT) ? t : 0;
    gates_kernel<<<dim3(64, 2, 2), 1024, 0, stream>>>(
        xs_bf + (size_t)tc * 64 * 256,
        actx_bf,
        ah_bf + (size_t)((t + 1) & 1) * 65536, ah_bf + (size_t)(t & 1) * 65536,
        dh_bf + (size_t)(t & 1) * 65536,       dh_bf + (size_t)((t + 1) & 1) * 65536,
        Wa_pack, Wd_pack, b_a, b_d, ah, ac, dh, dc, t);
    fused_step_kernel<<<128, 1024, 0, stream>>>(
        ah, dh, actx, actx_bf, aw, awcum, pmT, Wq, Wconv, Wloc, vvec,
        lens, enc, Wp, bp, outsOut, alignsOut, t);
  }
}